// Round 1
// baseline (204.623 us; speedup 1.0000x reference)
//
#include <hip/hip_runtime.h>
#include <math.h>

#define BB 8
#define HH 256
#define WW 256
#define TILE 8   // rows per block in pass 1

// Workspace layout: g[m][b][y][x], m = (c-1)*2 + pn  (pn: 0 = dist-to-pos-mask, 1 = dist-to-neg-mask)
// g holds SQUARED 1-D distances along H (column pass done first; envelope along W in pass 2).
// Pass-order swap vs reference is exact: all values are integers < 2^24 in fp32, and
// "INF" candidates (>= 513^2) never beat real candidates (<= 2*255^2) for non-empty masks.

__global__ __launch_bounds__(256) void edt_pass1(const int* __restrict__ tgt,
                                                 float* __restrict__ g) {
  const int x  = threadIdx.x;       // 0..255
  const int b  = blockIdx.x;        // 0..7
  const int y0 = blockIdx.y * TILE; // row tile base

  int dp[3][TILE], dn[3][TILE];
#pragma unroll
  for (int j = 0; j < TILE; ++j) {
    int y = y0 + j;
    // equivalent to reference's min(fwd,rev) scan result when no mask pixel in column
    int ini = min(513 + y, 768 - y);
#pragma unroll
    for (int c = 0; c < 3; ++c) { dp[c][j] = ini; dn[c][j] = ini; }
  }

  const int* tcol = tgt + b * HH * WW + x;
  for (int yp = 0; yp < HH; ++yp) {
    int e = tcol[yp * WW];          // coalesced across threads (x contiguous)
    bool is1 = (e == 1), is2 = (e == 2), is3 = (e == 3);
#pragma unroll
    for (int j = 0; j < TILE; ++j) {
      int ady = abs(y0 + j - yp);
      dp[0][j] = is1 ? min(dp[0][j], ady) : dp[0][j];
      dn[0][j] = is1 ? dn[0][j] : min(dn[0][j], ady);
      dp[1][j] = is2 ? min(dp[1][j], ady) : dp[1][j];
      dn[1][j] = is2 ? dn[1][j] : min(dn[1][j], ady);
      dp[2][j] = is3 ? min(dp[2][j], ady) : dp[2][j];
      dn[2][j] = is3 ? dn[2][j] : min(dn[2][j], ady);
    }
  }

#pragma unroll
  for (int j = 0; j < TILE; ++j) {
    int y = y0 + j;
#pragma unroll
    for (int c = 0; c < 3; ++c) {
      float gp = (float)(dp[c][j] * dp[c][j]);
      float gn = (float)(dn[c][j] * dn[c][j]);
      g[(((c * 2 + 0) * BB + b) * HH + y) * WW + x] = gp;  // coalesced
      g[(((c * 2 + 1) * BB + b) * HH + y) * WW + x] = gn;
    }
  }
}

__global__ __launch_bounds__(256) void edt_pass2(const float* __restrict__ g,
                                                 const int* __restrict__ tgt,
                                                 const float* __restrict__ preds,
                                                 float* __restrict__ out) {
  __shared__ float lds[6][WW];
  __shared__ float red[4];
  const int x = threadIdx.x;   // 0..255
  const int b = blockIdx.x;    // 0..7
  const int y = blockIdx.y;    // 0..255

#pragma unroll
  for (int m = 0; m < 6; ++m)
    lds[m][x] = g[((m * BB + b) * HH + y) * WW + x];   // coalesced
  __syncthreads();

  float d2[6];
#pragma unroll
  for (int m = 0; m < 6; ++m) d2[m] = 1e30f;

  // exact lower envelope along W: d2[x] = min_{x'} g[x'] + (x-x')^2
  for (int xp = 0; xp < WW; ++xp) {
    float fdx  = (float)(x - xp);
    float fdx2 = fdx * fdx;
#pragma unroll
    for (int m = 0; m < 6; ++m)
      d2[m] = fminf(d2[m], lds[m][xp] + fdx2);  // LDS broadcast read, no conflicts
  }

  const int t = tgt[(b * HH + y) * WW + x];
  const float* pb = preds + ((size_t)(b * 4) * HH + y) * WW + x;
  float p0 = pb[0];
  float p1 = pb[1 * HH * WW];
  float p2 = pb[2 * HH * WW];
  float p3 = pb[3 * HH * WW];
  float pm = fmaxf(fmaxf(p0, p1), fmaxf(p2, p3));
  float e0 = expf(p0 - pm), e1 = expf(p1 - pm), e2 = expf(p2 - pm), e3 = expf(p3 - pm);
  float inv = 1.0f / (e0 + e1 + e2 + e3);

  float contrib = 0.0f;
#pragma unroll
  for (int c = 0; c < 3; ++c) {
    float dpos = sqrtf(d2[c * 2 + 0]);
    float dneg = sqrtf(d2[c * 2 + 1]);
    bool  pos  = (t == c + 1);
    // dmap = pos ? (1 - dneg) : dpos   (edt(pos)=0 at pos pixels, edt(neg)=0 at neg pixels)
    float dmap = pos ? (1.0f - dneg) : dpos;
    float pc   = (c == 0) ? e1 : (c == 1) ? e2 : e3;
    contrib += dmap * pc;
  }
  contrib *= inv;

  // block reduction: wave64 shuffle, then 4 partials through LDS
  float v = contrib;
#pragma unroll
  for (int off = 32; off > 0; off >>= 1) v += __shfl_down(v, off, 64);
  if ((x & 63) == 0) red[x >> 6] = v;
  __syncthreads();
  if (x == 0) {
    float s = red[0] + red[1] + red[2] + red[3];
    atomicAdd(out, s * (1.0f / (3.0f * BB * HH * WW)));
  }
}

extern "C" void kernel_launch(void* const* d_in, const int* in_sizes, int n_in,
                              void* d_out, int out_size, void* d_ws, size_t ws_size,
                              hipStream_t stream) {
  const float* preds = (const float*)d_in[0];
  const int*   tgt   = (const int*)d_in[1];
  float* out = (float*)d_out;
  float* g   = (float*)d_ws;   // needs 6*B*H*W*4 = 12.58 MB

  hipMemsetAsync(out, 0, sizeof(float), stream);
  edt_pass1<<<dim3(BB, HH / TILE), 256, 0, stream>>>(tgt, g);
  edt_pass2<<<dim3(BB, HH), 256, 0, stream>>>(g, tgt, preds, out);
}

// Round 2
// 88.372 us; speedup vs baseline: 2.3155x; 2.3155x over previous
//
#include <hip/hip_runtime.h>
#include <math.h>

#define BB 8
#define HH 256
#define WW 256
#define T  2     // rows per fused block (must divide 64)
#define NW 4     // 256 rows / 64 bits

typedef unsigned long long u64;

// ---------------------------------------------------------------------------
// K0: per-column class presence bitmasks.
// masks[((b*4 + k)*NW + w)*WW + x] bit ly  <=>  tgt[b][w*64+ly][x] == k
// ---------------------------------------------------------------------------
__global__ __launch_bounds__(256) void build_masks(const int* __restrict__ tgt,
                                                   u64* __restrict__ masks) {
  const int x = threadIdx.x;
  const int b = blockIdx.x;
  const int w = blockIdx.y;
  u64 m0 = 0, m1 = 0, m2 = 0, m3 = 0, bit = 1ull;
  const int* p = tgt + ((size_t)b * HH + w * 64) * WW + x;
  for (int ly = 0; ly < 64; ++ly, bit += bit) {
    int e = p[ly * WW];                 // coalesced across x, L2-resident
    m0 |= (e == 0) ? bit : 0ull;
    m1 |= (e == 1) ? bit : 0ull;
    m2 |= (e == 2) ? bit : 0ull;
    m3 |= (e == 3) ? bit : 0ull;
  }
  const size_t base = (size_t)b * 4 * NW * WW + (size_t)w * WW + x;
  masks[base + 0 * NW * WW] = m0;
  masks[base + 1 * NW * WW] = m1;
  masks[base + 2 * NW * WW] = m2;
  masks[base + 3 * NW * WW] = m3;
}

// ---------------------------------------------------------------------------
// K1 fused: bitmask column-EDT -> LDS -> windowed exact envelope along x ->
// softmax epilogue -> block reduce -> one atomicAdd.
// dist-to-neg(c) == min_{j != c} dist-to-class(j): only 4 maps needed.
// Empty-column init min(513+y, 768-y) reproduces the reference's INF scans
// exactly (verified absmax 0.0 in R1).
// ---------------------------------------------------------------------------
__global__ __launch_bounds__(256, 2) void fused(const u64* __restrict__ masks,
                                                const int* __restrict__ tgt,
                                                const float* __restrict__ preds,
                                                float* __restrict__ out) {
  __shared__ float g[T][WW][4];   // squared 1-D column distances, 4 classes
  __shared__ int   wred[4];
  __shared__ float fred[4];
  const int x  = threadIdx.x;
  const int b  = blockIdx.x;
  const int y0 = blockIdx.y * T;
  const int wy = y0 >> 6;         // T divides 64 -> same word for all tile rows

  // column masks for this x: 4 classes x 4 words
  u64 m[4][NW];
#pragma unroll
  for (int k = 0; k < 4; ++k)
#pragma unroll
    for (int w = 0; w < NW; ++w)
      m[k][w] = masks[(((size_t)b * 4 + k) * NW + w) * WW + x];

  // phase A: exact 1-D distance along the column via nearest-set-bit
  int lmax = 0;
#pragma unroll
  for (int j = 0; j < T; ++j) {
    const int y  = y0 + j;
    const int ly = y & 63;
    const int ini = min(513 + y, 768 - y);   // reference INF-scan value
    float4 gv;
    float* gp = (float*)&gv;
#pragma unroll
    for (int k = 0; k < 4; ++k) {
      int best = ini;
#pragma unroll
      for (int w = 0; w < NW; ++w) {
        u64 bits = m[k][w];
        if (w < wy) {              // wave-uniform branch (wy is scalar)
          int d = y - (w * 64 + 63 - __clzll((long long)bits));
          best = min(best, bits ? d : 1024);
        } else if (w > wy) {
          int d = w * 64 + (__ffsll((long long)bits) - 1) - y;
          best = min(best, bits ? d : 1024);
        } else {
          u64 lo = bits & ((2ull << ly) - 1ull);  // bits 0..ly (ly=63 -> ~0)
          u64 hi = bits >> ly;                    // bit0 == bit ly
          int dl = ly - 63 + __clzll((long long)lo);
          int dh = __ffsll((long long)hi) - 1;
          best = min(best, lo ? dl : 1024);
          best = min(best, hi ? dh : 1024);
        }
      }
      lmax = max(lmax, best);
      gp[k] = (float)(best * best);
    }
    *(float4*)&g[j][x][0] = gv;
  }

  // block max of 1-D distances -> exact search radius R for the envelope:
  // for pixel x, xp=x gives d2 <= g[x] <= R^2, so |dx| > R can never win.
#pragma unroll
  for (int off = 32; off; off >>= 1) lmax = max(lmax, __shfl_xor(lmax, off, 64));
  if ((x & 63) == 0) wred[x >> 6] = lmax;
  __syncthreads();
  const int R = max(max(wred[0], wred[1]), max(wred[2], wred[3]));

  float acc = 0.0f;
#pragma unroll
  for (int j = 0; j < T; ++j) {
    const int y = y0 + j;
    float d0 = 1e30f, d1 = 1e30f, d2 = 1e30f, d3 = 1e30f;
#pragma unroll 4
    for (int kk = -R; kk <= R; ++kk) {
      int xp = min(max(x + kk, 0), WW - 1);   // clamp: duplicate candidates ok
      float dx  = (float)(x - xp);
      float dx2 = dx * dx;
      float4 gv = *(const float4*)&g[j][xp][0];
      d0 = fminf(d0, gv.x + dx2);
      d1 = fminf(d1, gv.y + dx2);
      d2 = fminf(d2, gv.z + dx2);
      d3 = fminf(d3, gv.w + dx2);
    }

    // epilogue: softmax + boundary map (same math as R1's passing kernel)
    const int t = tgt[((size_t)b * HH + y) * WW + x];
    const float* pb = preds + ((size_t)b * 4 * HH + y) * WW + x;
    float p0 = pb[0 * HH * WW], p1 = pb[1 * HH * WW];
    float p2 = pb[2 * HH * WW], p3 = pb[3 * HH * WW];
    float pm = fmaxf(fmaxf(p0, p1), fmaxf(p2, p3));
    float e0 = expf(p0 - pm), e1 = expf(p1 - pm);
    float e2 = expf(p2 - pm), e3 = expf(p3 - pm);
    float inv = 1.0f / (e0 + e1 + e2 + e3);

    float dn1 = fminf(d0, fminf(d2, d3));
    float dn2 = fminf(d0, fminf(d1, d3));
    float dn3 = fminf(d0, fminf(d1, d2));
    float c1 = (t == 1) ? (1.0f - sqrtf(dn1)) : sqrtf(d1);
    float c2 = (t == 2) ? (1.0f - sqrtf(dn2)) : sqrtf(d2);
    float c3 = (t == 3) ? (1.0f - sqrtf(dn3)) : sqrtf(d3);
    acc += (c1 * e1 + c2 * e2 + c3 * e3) * inv;
  }

  // block reduction -> single atomic
#pragma unroll
  for (int off = 32; off; off >>= 1) acc += __shfl_down(acc, off, 64);
  if ((x & 63) == 0) fred[x >> 6] = acc;
  __syncthreads();
  if (x == 0)
    atomicAdd(out, (fred[0] + fred[1] + fred[2] + fred[3]) *
                       (1.0f / (3.0f * BB * HH * WW)));
}

extern "C" void kernel_launch(void* const* d_in, const int* in_sizes, int n_in,
                              void* d_out, int out_size, void* d_ws, size_t ws_size,
                              hipStream_t stream) {
  const float* preds = (const float*)d_in[0];
  const int*   tgt   = (const int*)d_in[1];
  float* out   = (float*)d_out;
  u64*   masks = (u64*)d_ws;   // 8*4*4*256*8B = 256 KB

  hipMemsetAsync(out, 0, sizeof(float), stream);
  build_masks<<<dim3(BB, NW), 256, 0, stream>>>(tgt, masks);
  fused<<<dim3(BB, HH / T), 256, 0, stream>>>(masks, tgt, preds, out);
}

// Round 3
// 85.627 us; speedup vs baseline: 2.3897x; 1.0321x over previous
//
#include <hip/hip_runtime.h>
#include <math.h>

#define BB 8
#define HH 256
#define WW 256
#define T  2     // rows per fused block (must divide 64)
#define NW 4     // 256 rows / 64 bits
#define PAD 96   // envelope window padding; R>PAD handled by exact fallback
#define LDSW (WW + 2 * PAD)

typedef unsigned long long u64;

// ---------------------------------------------------------------------------
// K0: per-column class presence bitmasks + zero the output accumulator.
// masks[((b*4 + k)*NW + w)*WW + x] bit ly  <=>  tgt[b][w*64+ly][x] == k
// ---------------------------------------------------------------------------
__global__ __launch_bounds__(256) void build_masks(const int* __restrict__ tgt,
                                                   u64* __restrict__ masks,
                                                   float* __restrict__ out) {
  const int x = threadIdx.x;
  const int b = blockIdx.x;
  const int w = blockIdx.y;
  if (b == 0 && w == 0 && x == 0) out[0] = 0.0f;  // ordered before fused's atomics
  u64 m0 = 0, m1 = 0, m2 = 0, m3 = 0, bit = 1ull;
  const int* p = tgt + ((size_t)b * HH + w * 64) * WW + x;
  for (int ly = 0; ly < 64; ++ly, bit += bit) {
    int e = p[ly * WW];                 // coalesced across x, L2-resident
    m0 |= (e == 0) ? bit : 0ull;
    m1 |= (e == 1) ? bit : 0ull;
    m2 |= (e == 2) ? bit : 0ull;
    m3 |= (e == 3) ? bit : 0ull;
  }
  const size_t base = (size_t)b * 4 * NW * WW + (size_t)w * WW + x;
  masks[base + 0 * NW * WW] = m0;
  masks[base + 1 * NW * WW] = m1;
  masks[base + 2 * NW * WW] = m2;
  masks[base + 3 * NW * WW] = m3;
}

// ---------------------------------------------------------------------------
// K1 fused: bitmask column-EDT -> padded LDS -> exact +/- paired envelope
// (per-wave radius) -> softmax epilogue -> block reduce -> one atomicAdd.
// dist-to-neg(c) == min_{j != c} dist-to-class(j): only 4 maps needed.
// ---------------------------------------------------------------------------
__global__ __launch_bounds__(256, 4) void fused(const u64* __restrict__ masks,
                                                const int* __restrict__ tgt,
                                                const float* __restrict__ preds,
                                                float* __restrict__ out) {
  __shared__ float g[T][LDSW][4];   // squared 1-D column distances, padded rows
  __shared__ float fred[4];
  const int x  = threadIdx.x;
  const int b  = blockIdx.x;
  const int y0 = blockIdx.y * T;
  const int wy = y0 >> 6;           // T divides 64 -> same word for all tile rows

  // init padding to +INF (disjoint from the g[.][x+PAD] slots written below)
  for (int i = x; i < T * 2 * PAD; i += 256) {
    int j = i / (2 * PAD);
    int q = i - j * (2 * PAD);
    int idx = (q < PAD) ? q : (q + WW);
    *(float4*)&g[j][idx][0] = make_float4(1e30f, 1e30f, 1e30f, 1e30f);
  }

  // column masks for this x: 4 classes x 4 words
  u64 m[4][NW];
#pragma unroll
  for (int k = 0; k < 4; ++k)
#pragma unroll
    for (int w = 0; w < NW; ++w)
      m[k][w] = masks[(((size_t)b * 4 + k) * NW + w) * WW + x];

  // phase A: exact 1-D distance along the column via nearest-set-bit
  // (identical math to R2, verified absmax 0.0)
  int lmax = 0;
#pragma unroll
  for (int j = 0; j < T; ++j) {
    const int y  = y0 + j;
    const int ly = y & 63;
    const int ini = min(513 + y, 768 - y);   // reference INF-scan value
    float4 gv;
    float* gp = (float*)&gv;
#pragma unroll
    for (int k = 0; k < 4; ++k) {
      int best = ini;
#pragma unroll
      for (int w = 0; w < NW; ++w) {
        u64 bits = m[k][w];
        if (w < wy) {              // wave-uniform branch (wy is scalar)
          int d = y - (w * 64 + 63 - __clzll((long long)bits));
          best = min(best, bits ? d : 1024);
        } else if (w > wy) {
          int d = w * 64 + (__ffsll((long long)bits) - 1) - y;
          best = min(best, bits ? d : 1024);
        } else {
          u64 lo = bits & ((2ull << ly) - 1ull);  // bits 0..ly (ly=63 -> ~0)
          u64 hi = bits >> ly;                    // bit0 == bit ly
          int dl = ly - 63 + __clzll((long long)lo);
          int dh = __ffsll((long long)hi) - 1;
          best = min(best, lo ? dl : 1024);
          best = min(best, hi ? dh : 1024);
        }
      }
      lmax = max(lmax, best);
      gp[k] = (float)(best * best);
    }
    *(float4*)&g[j][x + PAD][0] = gv;
  }

  // per-wave radius: for pixel x, candidate |kk| >= dist(x) can't beat the
  // kk=0 seed (kk^2 >= g[x]); dist(x) <= wave-max over own lanes. Exact.
#pragma unroll
  for (int off = 32; off; off >>= 1) lmax = max(lmax, __shfl_xor(lmax, off, 64));
  const int R  = __builtin_amdgcn_readfirstlane(lmax);
  const int Rw = min(R, PAD);
  __syncthreads();

  // seed with own column value (kk = 0)
  float d[T][4];
#pragma unroll
  for (int j = 0; j < T; ++j) {
    float4 own = *(const float4*)&g[j][x + PAD][0];
    d[j][0] = own.x; d[j][1] = own.y; d[j][2] = own.z; d[j][3] = own.w;
  }

  // exact lower envelope, +/- paired, wave-uniform dx^2
  for (int kk = 1; kk <= Rw; ++kk) {
    float fkk = (float)kk;
    float fk2 = fkk * fkk;
#pragma unroll
    for (int j = 0; j < T; ++j) {
      float4 gm = *(const float4*)&g[j][x + PAD - kk][0];
      float4 gp = *(const float4*)&g[j][x + PAD + kk][0];
      d[j][0] = fminf(d[j][0], fminf(gm.x, gp.x) + fk2);
      d[j][1] = fminf(d[j][1], fminf(gm.y, gp.y) + fk2);
      d[j][2] = fminf(d[j][2], fminf(gm.z, gp.z) + fk2);
      d[j][3] = fminf(d[j][3], fminf(gm.w, gp.w) + fk2);
    }
  }
  if (R > PAD) {                       // exactness fallback; never hot
#pragma unroll 1
    for (int kk = PAD + 1; kk <= R; ++kk) {
      int xm = max(x - kk, 0), xp = min(x + kk, WW - 1);
      float dm = (float)(x - xm), dpq = (float)(xp - x);
      float dm2 = dm * dm, dp2 = dpq * dpq;
#pragma unroll
      for (int j = 0; j < T; ++j) {
        float4 gm = *(const float4*)&g[j][xm + PAD][0];
        float4 gp = *(const float4*)&g[j][xp + PAD][0];
        d[j][0] = fminf(d[j][0], fminf(gm.x + dm2, gp.x + dp2));
        d[j][1] = fminf(d[j][1], fminf(gm.y + dm2, gp.y + dp2));
        d[j][2] = fminf(d[j][2], fminf(gm.z + dm2, gp.z + dp2));
        d[j][3] = fminf(d[j][3], fminf(gm.w + dm2, gp.w + dp2));
      }
    }
  }

  // epilogue: softmax + boundary map (same math as R2's passing kernel)
  float acc = 0.0f;
#pragma unroll
  for (int j = 0; j < T; ++j) {
    const int y = y0 + j;
    const int t = tgt[((size_t)b * HH + y) * WW + x];
    const float* pb = preds + ((size_t)b * 4 * HH + y) * WW + x;
    float p0 = pb[0 * HH * WW], p1 = pb[1 * HH * WW];
    float p2 = pb[2 * HH * WW], p3 = pb[3 * HH * WW];
    float pm = fmaxf(fmaxf(p0, p1), fmaxf(p2, p3));
    float e0 = expf(p0 - pm), e1 = expf(p1 - pm);
    float e2 = expf(p2 - pm), e3 = expf(p3 - pm);
    float inv = 1.0f / (e0 + e1 + e2 + e3);

    float dn1 = fminf(d[j][0], fminf(d[j][2], d[j][3]));
    float dn2 = fminf(d[j][0], fminf(d[j][1], d[j][3]));
    float dn3 = fminf(d[j][0], fminf(d[j][1], d[j][2]));
    float c1 = (t == 1) ? (1.0f - sqrtf(dn1)) : sqrtf(d[j][1]);
    float c2 = (t == 2) ? (1.0f - sqrtf(dn2)) : sqrtf(d[j][2]);
    float c3 = (t == 3) ? (1.0f - sqrtf(dn3)) : sqrtf(d[j][3]);
    acc += (c1 * e1 + c2 * e2 + c3 * e3) * inv;
  }

  // block reduction -> single atomic
#pragma unroll
  for (int off = 32; off; off >>= 1) acc += __shfl_down(acc, off, 64);
  if ((x & 63) == 0) fred[x >> 6] = acc;
  __syncthreads();
  if (x == 0)
    atomicAdd(out, (fred[0] + fred[1] + fred[2] + fred[3]) *
                       (1.0f / (3.0f * BB * HH * WW)));
}

extern "C" void kernel_launch(void* const* d_in, const int* in_sizes, int n_in,
                              void* d_out, int out_size, void* d_ws, size_t ws_size,
                              hipStream_t stream) {
  const float* preds = (const float*)d_in[0];
  const int*   tgt   = (const int*)d_in[1];
  float* out   = (float*)d_out;
  u64*   masks = (u64*)d_ws;   // 8*4*4*256*8B = 256 KB

  build_masks<<<dim3(BB, NW), 256, 0, stream>>>(tgt, masks, out);
  fused<<<dim3(BB, HH / T), 256, 0, stream>>>(masks, tgt, preds, out);
}